// Round 2
// baseline (158.344 us; speedup 1.0000x reference)
//
#include <hip/hip_runtime.h>

typedef unsigned short u16;
typedef unsigned int u32;
typedef __attribute__((ext_vector_type(4))) float f32x4;
typedef __attribute__((ext_vector_type(8))) short bf16x8;
typedef __attribute__((ext_vector_type(8))) unsigned short u16x8;

#define SEQ   2048
#define NB    2
#define NH    8
#define HD    128
#define EMB   1024
#define WIN   128
#define MTOT  4096      // NB*SEQ
#define NQKV  3072
#define HSZ   (SEQ*HD)          // elements per (b,h) plane
#define QKVSZ (NB*NH*HSZ)       // 4194304 elements per q/k/v tensor

static __device__ __forceinline__ u16 f2bf(float f){
  u32 x = __builtin_bit_cast(u32, f);
  x += 0x7fffu + ((x >> 16) & 1u);          // round-to-nearest-even
  return (u16)(x >> 16);
}

static __device__ __forceinline__ void gload_lds16(const void* g, void* l){
  __builtin_amdgcn_global_load_lds((__attribute__((address_space(1))) void*)(void*)(g),
                                   (__attribute__((address_space(3))) void*)(l), 16, 0, 0);
}

#define VMW(n) asm volatile("s_waitcnt vmcnt(" #n ")" ::: "memory")

// ---------------- converts ----------------

__global__ __launch_bounds__(256) void cvt_bf16(const float* __restrict__ in,
                                                u16* __restrict__ out, int n){
  int i = (blockIdx.x * 256 + threadIdx.x) * 8;
  const int stride = gridDim.x * 256 * 8;
  for (; i < n; i += stride){
    float4 a = *(const float4*)(in + i);
    float4 b = *(const float4*)(in + i + 4);
    uint4 o;
    o.x = (u32)f2bf(a.x) | ((u32)f2bf(a.y) << 16);
    o.y = (u32)f2bf(a.z) | ((u32)f2bf(a.w) << 16);
    o.z = (u32)f2bf(b.x) | ((u32)f2bf(b.y) << 16);
    o.w = (u32)f2bf(b.z) | ((u32)f2bf(b.w) << 16);
    *(uint4*)(out + i) = o;
  }
}

// in[R][C] fp32 -> out[C][R] bf16
__global__ __launch_bounds__(256) void transpose_cvt(const float* __restrict__ in,
                                                     u16* __restrict__ out, int R, int C){
  __shared__ float tile[32][33];
  const int bx = blockIdx.x * 32;   // along C
  const int by = blockIdx.y * 32;   // along R
  const int tx = threadIdx.x & 31, ty = threadIdx.x >> 5;   // 32 x 8
  #pragma unroll
  for (int i = 0; i < 32; i += 8)
    tile[ty + i][tx] = in[(size_t)(by + ty + i) * C + bx + tx];
  __syncthreads();
  #pragma unroll
  for (int i = 0; i < 32; i += 8)
    out[(size_t)(bx + ty + i) * R + by + tx] = f2bf(tile[tx][ty + i]);
}

// ---------------- 256x256 8-phase GEMM (QKV): C = A[M,K] * Bt[N,K]^T + bias --
// 8 waves (2M x 4N), per-wave 128x64 output, BK=64, double-buffered 128 KiB LDS.
// T2 swizzle ((row&7)<<4), T3+T4 8-phase counted-vmcnt(2), T5 setprio, T1 XCD swz.
// Epilogue scatters q,k,v -> [B,H,T,D] bf16 with bias.

#define SLOTB 32768   // bytes of one 256x64 bf16 tile

__global__ __launch_bounds__(512, 2) void gemm256_qkv(
    const u16* __restrict__ A,     // [4096][1024] bf16
    const u16* __restrict__ Bt,    // [3072][1024] bf16
    const float* __restrict__ bias,
    u16* __restrict__ obf)         // qkv base
{
  constexpr int K = 1024;
  constexpr int NIT = K / 128;     // 8 iterations, 2 K-tiles each
  __shared__ char sm[131072];
  char* smA = sm;                  // [2 slots][256 rows][128 B]
  char* smB = sm + 2 * SLOTB;

  const int tid = threadIdx.x, lane = tid & 63, w = tid >> 6;
  const int wr = w >> 2, wc = w & 3;
  const int fr = lane & 15, hk = lane >> 4;

  // XCD-aware bijective swizzle (nwg = 192, 192 % 8 == 0)
  const int nwg = 16 * 12;
  const int bid = blockIdx.x;
  const int swz = (bid & 7) * (nwg >> 3) + (bid >> 3);
  const int bx = swz % 12, by = swz / 12;
  const int m0 = by * 256, n0 = bx * 256;

  // staging source (pre-swizzled column so linear LDS dest ends up swizzled)
  const int srow = lane >> 3;                          // row % 8 of this lane's dest
  const int scol = (((lane & 7) ^ srow) << 3);         // elems
  const u16* ag = A  + (size_t)(m0 + w * 8 + srow) * K + scol;
  const u16* bg = Bt + (size_t)(n0 + w * 8 + srow) * K + scol;

  auto STG = [&](int slot, int abm, int h, int kt){
    const u16* s = (abm ? bg : ag) + (size_t)h * 128 * K + kt * 64;
    char* d = (abm ? smB : smA) + slot * SLOTB + h * 16384 + w * 1024;
    gload_lds16(s, d);              // rows h*128 + w*8 + [0,8)
    gload_lds16(s + 64 * K, d + 8192);   // rows +64
  };

  auto LDA = [&](int slot, int mh, int mi, int ks) -> bf16x8 {
    const int r = wr * 128 + mh * 64 + mi * 16 + fr;
    const int cb = (ks * 64 + hk * 16) ^ ((r & 7) << 4);
    return *(const bf16x8*)(smA + slot * SLOTB + r * 128 + cb);
  };
  auto LDB = [&](int slot, int nh, int ni, int ks) -> bf16x8 {
    const int r = wc * 64 + nh * 32 + ni * 16 + fr;
    const int cb = (ks * 64 + hk * 16) ^ ((r & 7) << 4);
    return *(const bf16x8*)(smB + slot * SLOTB + r * 128 + cb);
  };

  bf16x8 a[4][2], b[2][2][2];
  f32x4 acc[8][4] = {};

  auto RDA = [&](int slot, int mh){
    #pragma unroll
    for (int mi = 0; mi < 4; ++mi)
      #pragma unroll
      for (int ks = 0; ks < 2; ++ks) a[mi][ks] = LDA(slot, mh, mi, ks);
  };
  auto RDB = [&](int slot, int nh){
    #pragma unroll
    for (int ni = 0; ni < 2; ++ni)
      #pragma unroll
      for (int ks = 0; ks < 2; ++ks) b[nh][ni][ks] = LDB(slot, nh, ni, ks);
  };
  auto MF = [&](int mh, int nh){
    __builtin_amdgcn_s_setprio(1);
    #pragma unroll
    for (int mi = 0; mi < 4; ++mi)
      #pragma unroll
      for (int ni = 0; ni < 2; ++ni)
        #pragma unroll
        for (int ks = 0; ks < 2; ++ks)
          acc[mh * 4 + mi][nh * 2 + ni] = __builtin_amdgcn_mfma_f32_16x16x32_bf16(
              a[mi][ks], b[nh][ni][ks], acc[mh * 4 + mi][nh * 2 + ni], 0, 0, 0);
    __builtin_amdgcn_s_setprio(0);
  };
  auto BAR = [&](){
    asm volatile("" ::: "memory");
    __builtin_amdgcn_s_barrier();
    asm volatile("" ::: "memory");
  };

  // prologue: tile0 (slot0) fully + tile1.Ah0; wait tile0; 10 -> 2 outstanding
  STG(0, 0, 0, 0); STG(0, 0, 1, 0); STG(0, 1, 0, 0); STG(0, 1, 1, 0);
  STG(1, 0, 0, 1);
  VMW(2);
  BAR();

  for (int i = 0; i < NIT; ++i){
    const int k1 = 2 * i + 1;
    const int k2 = (2 * i + 2) & 15;   // wraps harmlessly on last iter
    const int k3 = (2 * i + 3) & 15;
    // ph1: compute t0(slot0) quadrant (mh0,nh0); stage t1.Ah1
    RDA(0, 0); RDB(0, 0); STG(1, 0, 1, k1); BAR(); MF(0, 0); BAR();
    // ph2: (mh0,nh1); stage t1.Bh0
    RDB(0, 1); STG(1, 1, 0, k1); BAR(); MF(0, 1); BAR();
    // ph3: (mh1,nh1); stage t1.Bh1   (last reads of slot0)
    RDA(0, 1); STG(1, 1, 1, k1); BAR(); MF(1, 1); BAR();
    // ph4: (mh1,nh0); stage t2.Ah0 into slot0 (now safe); wait slot1 ready
    STG(0, 0, 0, k2); BAR(); MF(1, 0); VMW(2); BAR();
    // ph5-8: mirror on slot1, staging t2 tail + t3.Ah0
    RDA(1, 0); RDB(1, 0); STG(0, 0, 1, k2); BAR(); MF(0, 0); BAR();
    RDB(1, 1); STG(0, 1, 0, k2); BAR(); MF(0, 1); BAR();
    RDA(1, 1); STG(0, 1, 1, k2); BAR(); MF(1, 1); BAR();
    STG(1, 0, 0, k3); BAR(); MF(1, 0); VMW(2); BAR();
  }

  VMW(0);   // drain stray (wrapped) stages before LDS goes away

  // epilogue: C row = (hk<<2)+j, col = fr; scatter to q/k/v [B,H,T,D] bf16
  #pragma unroll
  for (int mi = 0; mi < 8; ++mi){
    const int rg = m0 + wr * 128 + mi * 16 + (hk << 2);
    const int b_ = rg >> 11, t = rg & 2047;
    #pragma unroll
    for (int ni = 0; ni < 4; ++ni){
      const int cg = n0 + wc * 64 + ni * 16 + fr;
      const float bs = bias[cg];
      const int which = cg >> 10, hm = cg & 1023;
      u16* dst = obf + (size_t)which * QKVSZ
                     + ((size_t)(b_ * NH + (hm >> 7)) * SEQ + t) * HD + (hm & 127);
      #pragma unroll
      for (int j = 0; j < 4; ++j)
        dst[(size_t)j * HD] = f2bf(acc[mi][ni][j] + bs);
    }
  }
}

// ---------------- 128x128 GEMM (proj): of[M,N] = A[M,K]*Bt[N,K]^T + bias ----

__global__ __launch_bounds__(256) void gemm_proj(
    const u16* __restrict__ A,    // [M][1024] bf16
    const u16* __restrict__ Bt,   // [N][1024] bf16
    const float* __restrict__ bias,
    float* __restrict__ of)
{
  constexpr int K = 1024, BK = 64;
  __shared__ u16 As[128 * 64];
  __shared__ u16 Bs[128 * 64];
  const int tid = threadIdx.x, lane = tid & 63, wave = tid >> 6;
  const int m0 = blockIdx.y * 128, n0 = blockIdx.x * 128;
  const int wr = (wave >> 1) * 64, wc = (wave & 1) * 64;

  const int srow = lane >> 3;
  const int scol = ((((lane & 7) << 4) ^ (srow << 4)) >> 1);
  const u16* ag = A  + (size_t)(m0 + wave * 32 + srow) * K + scol;
  const u16* bg = Bt + (size_t)(n0 + wave * 32 + srow) * K + scol;
  u16* al = &As[wave * 32 * 64];
  u16* bl = &Bs[wave * 32 * 64];

  f32x4 acc[4][4] = {};

  for (int kt = 0; kt < K / BK; ++kt){
    #pragma unroll
    for (int j = 0; j < 4; ++j){
      gload_lds16(ag + (size_t)j * 8 * K + kt * BK, al + j * 8 * 64);
      gload_lds16(bg + (size_t)j * 8 * K + kt * BK, bl + j * 8 * 64);
    }
    __syncthreads();
    #pragma unroll
    for (int ks = 0; ks < 2; ++ks){
      const int fr = lane & 15;
      const int colb = ((ks << 6) + ((lane >> 4) << 4)) ^ ((lane & 7) << 4);
      bf16x8 af[4], bfr[4];
      #pragma unroll
      for (int mi = 0; mi < 4; ++mi)
        af[mi] = *(const bf16x8*)((const char*)As + (wr + mi * 16 + fr) * 128 + colb);
      #pragma unroll
      for (int ni = 0; ni < 4; ++ni)
        bfr[ni] = *(const bf16x8*)((const char*)Bs + (wc + ni * 16 + fr) * 128 + colb);
      #pragma unroll
      for (int mi = 0; mi < 4; ++mi)
        #pragma unroll
        for (int ni = 0; ni < 4; ++ni)
          acc[mi][ni] = __builtin_amdgcn_mfma_f32_16x16x32_bf16(af[mi], bfr[ni], acc[mi][ni], 0, 0, 0);
    }
    __syncthreads();
  }

  #pragma unroll
  for (int mi = 0; mi < 4; ++mi){
    const int rg = m0 + wr + mi * 16 + ((lane >> 4) << 2);
    #pragma unroll
    for (int ni = 0; ni < 4; ++ni){
      const int cg = n0 + wc + ni * 16 + (lane & 15);
      const float bs = bias[cg];
      #pragma unroll
      for (int j = 0; j < 4; ++j)
        of[(size_t)(rg + j) * EMB + cg] = acc[mi][ni][j] + bs;
    }
  }
}

// ---------------- sliding-window attention ----------------

__global__ __launch_bounds__(256) void attn_kernel(
    const u16* __restrict__ QKVb, const float* __restrict__ gate, u16* __restrict__ Ao)
{
  __shared__ float S[64 * 196];
  __shared__ u16 KV[128 * 72];
  const int tid = threadIdx.x, lane = tid & 63, wave = tid >> 6;
  const int q0 = blockIdx.x * 64;
  const int bh = blockIdx.y;
  const u16* Qg = QKVb + (size_t)bh * HSZ;
  const u16* Kg = QKVb + (size_t)QKVSZ + (size_t)bh * HSZ;
  const u16* Vg = QKVb + (size_t)2 * QKVSZ + (size_t)bh * HSZ;
  const int kstart = q0 - WIN;

  bf16x8 qf[4];
  {
    const u16* qp = Qg + (size_t)(q0 + wave * 16 + (lane & 15)) * HD + 8 * (lane >> 4);
    #pragma unroll
    for (int ks = 0; ks < 4; ++ks) qf[ks] = *(const bf16x8*)(qp + ks * 32);
  }
  const float scale = 0.08838834764831845f;

  for (int c = 0; c < 3; ++c){
    {
      const int keyl = tid >> 2;
      int krow = kstart + c * 64 + keyl;
      krow = min(max(krow, 0), SEQ - 1);
      const u16* kp = Kg + (size_t)krow * HD + (tid & 3) * 8;
      u16* ksh = &KV[keyl * 136 + (tid & 3) * 8];
      #pragma unroll
      for (int r = 0; r < 4; ++r)
        *(uint4*)(ksh + r * 32) = *(const uint4*)(kp + r * 32);
    }
    __syncthreads();
    f32x4 sacc[4] = {};
    #pragma unroll
    for (int ks = 0; ks < 4; ++ks){
      #pragma unroll
      for (int nf = 0; nf < 4; ++nf){
        bf16x8 kf = *(const bf16x8*)(&KV[(nf * 16 + (lane & 15)) * 136 + ks * 32 + 8 * (lane >> 4)]);
        sacc[nf] = __builtin_amdgcn_mfma_f32_16x16x32_bf16(qf[ks], kf, sacc[nf], 0, 0, 0);
      }
    }
    #pragma unroll
    for (int nf = 0; nf < 4; ++nf){
      const int kc = c * 64 + nf * 16 + (lane & 15);
      const int kg = kstart + kc;
      #pragma unroll
      for (int j = 0; j < 4; ++j){
        const int qr = wave * 16 + ((lane >> 4) << 2) + j;
        const int qg = q0 + qr;
        const bool ok = (kg >= 0) && (kg <= qg) && (qg - kg <= WIN);
        S[qr * 196 + kc] = ok ? sacc[nf][j] * scale : -1e30f;
      }
    }
    __syncthreads();
  }

  {
    const int r = tid >> 2, sub = tid & 3;
    float4 v[12];
    float mx = -1e30f;
    #pragma unroll
    for (int i = 0; i < 12; ++i){
      v[i] = *(const float4*)(&S[r * 196 + (sub + 4 * i) * 4]);
      mx = fmaxf(mx, fmaxf(fmaxf(v[i].x, v[i].y), fmaxf(v[i].z, v[i].w)));
    }
    mx = fmaxf(mx, __shfl_xor(mx, 1));
    mx = fmaxf(mx, __shfl_xor(mx, 2));
    float sum = 0.f;
    #pragma unroll
    for (int i = 0; i < 12; ++i){
      v[i].x = __expf(v[i].x - mx); v[i].y = __expf(v[i].y - mx);
      v[i].z = __expf(v[i].z - mx); v[i].w = __expf(v[i].w - mx);
      sum += v[i].x + v[i].y + v[i].z + v[i].w;
    }
    sum += __shfl_xor(sum, 1);
    sum += __shfl_xor(sum, 2);
    const float inv = 1.0f / sum;
    #pragma unroll
    for (int i = 0; i < 12; ++i){
      v[i].x *= inv; v[i].y *= inv; v[i].z *= inv; v[i].w *= inv;
      *(float4*)(&S[r * 196 + (sub + 4 * i) * 4]) = v[i];
    }
  }
  __syncthreads();

  f32x4 oacc[8] = {};
  for (int c = 0; c < 3; ++c){
    {
      const int keyl = tid & 63;
      int krow = kstart + c * 64 + keyl;
      krow = min(max(krow, 0), SEQ - 1);
      const u16* vp = Vg + (size_t)krow * HD + (tid >> 6) * 32;
      #pragma unroll
      for (int r2 = 0; r2 < 4; ++r2){
        u16x8 vv = *(const u16x8*)(vp + r2 * 8);
        const int dbase = (tid >> 6) * 32 + r2 * 8;
        #pragma unroll
        for (int j = 0; j < 8; ++j)
          KV[(dbase + j) * 72 + keyl] = vv[j];
      }
    }
    __syncthreads();
    #pragma unroll
    for (int ks = 0; ks < 2; ++ks){
      const float* sp = &S[(wave * 16 + (lane & 15)) * 196 + c * 64 + ks * 32 + 8 * (lane >> 4)];
      float4 p0 = *(const float4*)sp;
      float4 p1 = *(const float4*)(sp + 4);
      bf16x8 pf;
      pf[0] = (short)f2bf(p0.x); pf[1] = (short)f2bf(p0.y);
      pf[2] = (short)f2bf(p0.z); pf[3] = (short)f2bf(p0.w);
      pf[4] = (short)f2bf(p1.x); pf[5] = (short)f2bf(p1.y);
      pf[6] = (short)f2bf(p1.z); pf[7] = (short)f2bf(p1.w);
      #pragma unroll
      for (int nf = 0; nf < 8; ++nf){
        bf16x8 vf = *(const bf16x8*)(&KV[(nf * 16 + (lane & 15)) * 72 + ks * 32 + 8 * (lane >> 4)]);
        oacc[nf] = __builtin_amdgcn_mfma_f32_16x16x32_bf16(pf, vf, oacc[nf], 0, 0, 0);
      }
    }
    __syncthreads();
  }

  {
    const int b = bh >> 3, h = bh & 7;
    #pragma unroll
    for (int nf = 0; nf < 8; ++nf){
      const int d = nf * 16 + (lane & 15);
      const float gv = gate[h * HD + d];
      #pragma unroll
      for (int j = 0; j < 4; ++j){
        const int t = q0 + wave * 16 + ((lane >> 4) << 2) + j;
        Ao[((size_t)(b * SEQ + t)) * EMB + h * HD + d] = f2bf(oacc[nf][j] * gv);
      }
    }
  }
}

// ---------------- launch ----------------

extern "C" void kernel_launch(void* const* d_in, const int* in_sizes, int n_in,
                              void* d_out, int out_size, void* d_ws, size_t ws_size,
                              hipStream_t stream)
{
  const float* x     = (const float*)d_in[0];
  const float* Wqkv  = (const float*)d_in[1];
  const float* bqkv  = (const float*)d_in[2];
  const float* Wproj = (const float*)d_in[3];
  const float* bproj = (const float*)d_in[4];
  const float* gate  = (const float*)d_in[5];
  float* out = (float*)d_out;

  u16* Xb   = (u16*)d_ws;                        // [4096][1024]
  u16* Wqt  = Xb   + (size_t)MTOT * EMB;         // [3072][1024]
  u16* Wpt  = Wqt  + (size_t)NQKV * EMB;         // [1024][1024]
  u16* QKVb = Wpt  + (size_t)EMB * EMB;          // 3 x [B,H,T,D]
  u16* Ao   = QKVb + (size_t)3 * QKVSZ;          // [4096][1024] gated attn out

  cvt_bf16<<<dim3(2048), dim3(256), 0, stream>>>(x, Xb, MTOT * EMB);
  transpose_cvt<<<dim3(NQKV / 32, EMB / 32), dim3(256), 0, stream>>>(Wqkv, Wqt, EMB, NQKV);
  transpose_cvt<<<dim3(EMB / 32, EMB / 32), dim3(256), 0, stream>>>(Wproj, Wpt, EMB, EMB);

  gemm256_qkv<<<dim3(16 * 12), dim3(512), 0, stream>>>(Xb, Wqt, bqkv, QKVb);

  attn_kernel<<<dim3(SEQ / 64, NB * NH), dim3(256), 0, stream>>>(QKVb, gate, Ao);

  gemm_proj<<<dim3(EMB / 128, MTOT / 128), dim3(256), 0, stream>>>(Ao, Wpt, bproj, out);
}

// Round 3
// 148.098 us; speedup vs baseline: 1.0692x; 1.0692x over previous
//
#include <hip/hip_runtime.h>

typedef unsigned short u16;
typedef unsigned int u32;
typedef __attribute__((ext_vector_type(4))) float f32x4;
typedef __attribute__((ext_vector_type(8))) short bf16x8;
typedef __attribute__((ext_vector_type(8))) unsigned short u16x8;

#define SEQ   2048
#define NB    2
#define NH    8
#define HD    128
#define EMB   1024
#define WIN   128
#define MTOT  4096      // NB*SEQ
#define NQKV  3072
#define HSZ   (SEQ*HD)          // elements per (b,h) plane
#define QKVSZ (NB*NH*HSZ)       // 4194304 elements per q/k/v tensor

static __device__ __forceinline__ u16 f2bf(float f){
  u32 x = __builtin_bit_cast(u32, f);
  x += 0x7fffu + ((x >> 16) & 1u);          // round-to-nearest-even
  return (u16)(x >> 16);
}

static __device__ __forceinline__ void gload_lds16(const void* g, void* l){
  __builtin_amdgcn_global_load_lds((__attribute__((address_space(1))) void*)(void*)(g),
                                   (__attribute__((address_space(3))) void*)(l), 16, 0, 0);
}

// ---------------- fused prep: x->bf16, Wqkv^T->bf16, Wproj^T->bf16 ----------
// blocks [0,2048): cvt x (exact cover, 8 elem/thread)
// blocks [2048,5120): transpose Wqkv (96 x 32 tiles)
// blocks [5120,6144): transpose Wproj (32 x 32 tiles)

__global__ __launch_bounds__(256) void prep(
    const float* __restrict__ x, const float* __restrict__ Wqkv,
    const float* __restrict__ Wproj,
    u16* __restrict__ Xb, u16* __restrict__ Wqt, u16* __restrict__ Wpt)
{
  __shared__ float tile[32][33];
  const int b = blockIdx.x, tid = threadIdx.x;
  if (b < 2048){
    const int i = (b * 256 + tid) * 8;
    float4 a = *(const float4*)(x + i);
    float4 c = *(const float4*)(x + i + 4);
    uint4 o;
    o.x = (u32)f2bf(a.x) | ((u32)f2bf(a.y) << 16);
    o.y = (u32)f2bf(a.z) | ((u32)f2bf(a.w) << 16);
    o.z = (u32)f2bf(c.x) | ((u32)f2bf(c.y) << 16);
    o.w = (u32)f2bf(c.z) | ((u32)f2bf(c.w) << 16);
    *(uint4*)(Xb + i) = o;
    return;
  }
  const float* in; u16* out; int R, C, bxi, byi;
  if (b < 5120){
    const int bb = b - 2048;
    in = Wqkv; out = Wqt; R = EMB; C = NQKV;
    bxi = bb % 96; byi = bb / 96;
  } else {
    const int bb = b - 5120;
    in = Wproj; out = Wpt; R = EMB; C = EMB;
    bxi = bb & 31; byi = bb >> 5;
  }
  const int bx = bxi * 32, by = byi * 32;
  const int tx = tid & 31, ty = tid >> 5;   // 32 x 8
  #pragma unroll
  for (int i = 0; i < 32; i += 8)
    tile[ty + i][tx] = in[(size_t)(by + ty + i) * C + bx + tx];
  __syncthreads();
  #pragma unroll
  for (int i = 0; i < 32; i += 8)
    out[(size_t)(bx + ty + i) * R + by + tx] = f2bf(tile[tx][ty + i]);
}

// ---------------- QKV GEMM: 128x128 tile, scatter epilogue ----------------

__global__ __launch_bounds__(256) void gemm_qkv(
    const u16* __restrict__ A,    // [4096][1024] bf16
    const u16* __restrict__ Bt,   // [3072][1024] bf16
    const float* __restrict__ bias,
    u16* __restrict__ obf)        // qkv base
{
  constexpr int K = 1024, BK = 64;
  __shared__ u16 As[128 * 64];
  __shared__ u16 Bs[128 * 64];
  const int tid = threadIdx.x, lane = tid & 63, wave = tid >> 6;
  const int m0 = blockIdx.y * 128, n0 = blockIdx.x * 128;
  const int wr = (wave >> 1) * 64, wc = (wave & 1) * 64;

  const int srow = lane >> 3;                                   // 0..7
  const int scol = ((((lane & 7) << 4) ^ (srow << 4)) >> 1);    // pre-swizzled src col
  const u16* ag = A  + (size_t)(m0 + wave * 32 + srow) * K + scol;
  const u16* bg = Bt + (size_t)(n0 + wave * 32 + srow) * K + scol;
  u16* al = &As[wave * 32 * 64];
  u16* bl = &Bs[wave * 32 * 64];

  f32x4 acc[4][4] = {};

  for (int kt = 0; kt < K / BK; ++kt){
    #pragma unroll
    for (int j = 0; j < 4; ++j){
      gload_lds16(ag + (size_t)j * 8 * K + kt * BK, al + j * 8 * 64);
      gload_lds16(bg + (size_t)j * 8 * K + kt * BK, bl + j * 8 * 64);
    }
    __syncthreads();
    #pragma unroll
    for (int ks = 0; ks < 2; ++ks){
      const int fr = lane & 15;
      const int colb = ((ks << 6) + ((lane >> 4) << 4)) ^ ((lane & 7) << 4);
      bf16x8 af[4], bfr[4];
      #pragma unroll
      for (int mi = 0; mi < 4; ++mi)
        af[mi] = *(const bf16x8*)((const char*)As + (wr + mi * 16 + fr) * 128 + colb);
      #pragma unroll
      for (int ni = 0; ni < 4; ++ni)
        bfr[ni] = *(const bf16x8*)((const char*)Bs + (wc + ni * 16 + fr) * 128 + colb);
      #pragma unroll
      for (int mi = 0; mi < 4; ++mi)
        #pragma unroll
        for (int ni = 0; ni < 4; ++ni)
          acc[mi][ni] = __builtin_amdgcn_mfma_f32_16x16x32_bf16(af[mi], bfr[ni], acc[mi][ni], 0, 0, 0);
    }
    __syncthreads();
  }

  #pragma unroll
  for (int mi = 0; mi < 4; ++mi){
    const int rg = m0 + wr + mi * 16 + ((lane >> 4) << 2);
    const int b_ = rg >> 11, t = rg & 2047;
    #pragma unroll
    for (int ni = 0; ni < 4; ++ni){
      const int cg = n0 + wc + ni * 16 + (lane & 15);
      const float bs = bias[cg];
      const int which = cg >> 10, hm = cg & 1023;
      u16* dst = obf + (size_t)which * QKVSZ
                     + ((size_t)(b_ * NH + (hm >> 7)) * SEQ + t) * HD + (hm & 127);
      #pragma unroll
      for (int j = 0; j < 4; ++j)
        dst[(size_t)j * HD] = f2bf(acc[mi][ni][j] + bs);
    }
  }
}

// ---------------- proj GEMM: 128x64 tile -> 512 blocks (2/CU) ----------------
// 4 waves as 2M x 2N, each 64x32 output. LDS: A 16KB + B 8KB = 24KB.

__global__ __launch_bounds__(256) void gemm_proj(
    const u16* __restrict__ A,    // [4096][1024] bf16
    const u16* __restrict__ Bt,   // [1024][1024] bf16
    const float* __restrict__ bias,
    float* __restrict__ of)
{
  constexpr int K = 1024, BK = 64;
  __shared__ u16 As[128 * 64];
  __shared__ u16 Bs[64 * 64];
  const int tid = threadIdx.x, lane = tid & 63, wave = tid >> 6;
  const int m0 = blockIdx.y * 128, n0 = blockIdx.x * 64;
  const int wr = (wave >> 1) * 64, wc = (wave & 1) * 32;
  const int fr = lane & 15, hk = lane >> 4;

  // staging: chunk = round*256 + tid; row = chunk/8, swizzled source col
  const int prow = tid >> 3;                 // row within a 32-row round
  const int sw8 = (tid & 7) ^ (prow & 7);    // source 16B chunk within row
  const u16* ag = A  + (size_t)(m0 + prow) * K + sw8 * 8;
  const u16* bg = Bt + (size_t)(n0 + prow) * K + sw8 * 8;

  f32x4 acc[4][2] = {};

  for (int kt = 0; kt < K / BK; ++kt){
    #pragma unroll
    for (int r = 0; r < 4; ++r)
      gload_lds16(ag + (size_t)(r * 32) * K + kt * BK, (char*)As + r * 4096 + tid * 16);
    #pragma unroll
    for (int r = 0; r < 2; ++r)
      gload_lds16(bg + (size_t)(r * 32) * K + kt * BK, (char*)Bs + r * 4096 + tid * 16);
    __syncthreads();
    #pragma unroll
    for (int ks = 0; ks < 2; ++ks){
      bf16x8 af[4], bfr[2];
      #pragma unroll
      for (int mi = 0; mi < 4; ++mi){
        const int r = wr + mi * 16 + fr;
        const int cb = ((ks << 6) + (hk << 4)) ^ ((r & 7) << 4);
        af[mi] = *(const bf16x8*)((const char*)As + r * 128 + cb);
      }
      #pragma unroll
      for (int ni = 0; ni < 2; ++ni){
        const int r = wc + ni * 16 + fr;
        const int cb = ((ks << 6) + (hk << 4)) ^ ((r & 7) << 4);
        bfr[ni] = *(const bf16x8*)((const char*)Bs + r * 128 + cb);
      }
      #pragma unroll
      for (int mi = 0; mi < 4; ++mi)
        #pragma unroll
        for (int ni = 0; ni < 2; ++ni)
          acc[mi][ni] = __builtin_amdgcn_mfma_f32_16x16x32_bf16(af[mi], bfr[ni], acc[mi][ni], 0, 0, 0);
    }
    __syncthreads();
  }

  #pragma unroll
  for (int mi = 0; mi < 4; ++mi){
    const int rg = m0 + wr + mi * 16 + (hk << 2);
    #pragma unroll
    for (int ni = 0; ni < 2; ++ni){
      const int cg = n0 + wc + ni * 16 + fr;
      const float bs = bias[cg];
      #pragma unroll
      for (int j = 0; j < 4; ++j)
        of[(size_t)(rg + j) * EMB + cg] = acc[mi][ni][j] + bs;
    }
  }
}

// ---------------- sliding-window attention ----------------

__global__ __launch_bounds__(256) void attn_kernel(
    const u16* __restrict__ QKVb, const float* __restrict__ gate, u16* __restrict__ Ao)
{
  __shared__ float S[64 * 196];
  __shared__ u16 KV[128 * 72];
  const int tid = threadIdx.x, lane = tid & 63, wave = tid >> 6;
  const int q0 = blockIdx.x * 64;
  const int bh = blockIdx.y;
  const u16* Qg = QKVb + (size_t)bh * HSZ;
  const u16* Kg = QKVb + (size_t)QKVSZ + (size_t)bh * HSZ;
  const u16* Vg = QKVb + (size_t)2 * QKVSZ + (size_t)bh * HSZ;
  const int kstart = q0 - WIN;

  bf16x8 qf[4];
  {
    const u16* qp = Qg + (size_t)(q0 + wave * 16 + (lane & 15)) * HD + 8 * (lane >> 4);
    #pragma unroll
    for (int ks = 0; ks < 4; ++ks) qf[ks] = *(const bf16x8*)(qp + ks * 32);
  }
  const float scale = 0.08838834764831845f;

  for (int c = 0; c < 3; ++c){
    if (kstart + c * 64 + 64 <= 0){       // chunk entirely before t=0: mask-fill only
      for (int t2 = tid; t2 < 64 * 64; t2 += 256)
        S[(t2 >> 6) * 196 + c * 64 + (t2 & 63)] = -1e30f;
      continue;                            // block-uniform; later barriers cover ordering
    }
    {
      const int keyl = tid >> 2;
      int krow = kstart + c * 64 + keyl;
      krow = min(max(krow, 0), SEQ - 1);
      const u16* kp = Kg + (size_t)krow * HD + (tid & 3) * 8;
      u16* ksh = &KV[keyl * 136 + (tid & 3) * 8];
      #pragma unroll
      for (int r = 0; r < 4; ++r)
        *(uint4*)(ksh + r * 32) = *(const uint4*)(kp + r * 32);
    }
    __syncthreads();
    f32x4 sacc[4] = {};
    #pragma unroll
    for (int ks = 0; ks < 4; ++ks){
      #pragma unroll
      for (int nf = 0; nf < 4; ++nf){
        bf16x8 kf = *(const bf16x8*)(&KV[(nf * 16 + (lane & 15)) * 136 + ks * 32 + 8 * (lane >> 4)]);
        sacc[nf] = __builtin_amdgcn_mfma_f32_16x16x32_bf16(qf[ks], kf, sacc[nf], 0, 0, 0);
      }
    }
    #pragma unroll
    for (int nf = 0; nf < 4; ++nf){
      const int kc = c * 64 + nf * 16 + (lane & 15);
      const int kg = kstart + kc;
      #pragma unroll
      for (int j = 0; j < 4; ++j){
        const int qr = wave * 16 + ((lane >> 4) << 2) + j;
        const int qg = q0 + qr;
        const bool ok = (kg >= 0) && (kg <= qg) && (qg - kg <= WIN);
        S[qr * 196 + kc] = ok ? sacc[nf][j] * scale : -1e30f;
      }
    }
    __syncthreads();
  }

  {
    const int r = tid >> 2, sub = tid & 3;
    float4 v[12];
    float mx = -1e30f;
    #pragma unroll
    for (int i = 0; i < 12; ++i){
      v[i] = *(const float4*)(&S[r * 196 + (sub + 4 * i) * 4]);
      mx = fmaxf(mx, fmaxf(fmaxf(v[i].x, v[i].y), fmaxf(v[i].z, v[i].w)));
    }
    mx = fmaxf(mx, __shfl_xor(mx, 1));
    mx = fmaxf(mx, __shfl_xor(mx, 2));
    float sum = 0.f;
    #pragma unroll
    for (int i = 0; i < 12; ++i){
      v[i].x = __expf(v[i].x - mx); v[i].y = __expf(v[i].y - mx);
      v[i].z = __expf(v[i].z - mx); v[i].w = __expf(v[i].w - mx);
      sum += v[i].x + v[i].y + v[i].z + v[i].w;
    }
    sum += __shfl_xor(sum, 1);
    sum += __shfl_xor(sum, 2);
    const float inv = 1.0f / sum;
    #pragma unroll
    for (int i = 0; i < 12; ++i){
      v[i].x *= inv; v[i].y *= inv; v[i].z *= inv; v[i].w *= inv;
      *(float4*)(&S[r * 196 + (sub + 4 * i) * 4]) = v[i];
    }
  }
  __syncthreads();

  f32x4 oacc[8] = {};
  for (int c = 0; c < 3; ++c){
    if (kstart + c * 64 + 64 <= 0) continue;   // P==0 for this chunk
    {
      const int keyl = tid & 63;
      int krow = kstart + c * 64 + keyl;
      krow = min(max(krow, 0), SEQ - 1);
      const u16* vp = Vg + (size_t)krow * HD + (tid >> 6) * 32;
      #pragma unroll
      for (int r2 = 0; r2 < 4; ++r2){
        u16x8 vv = *(const u16x8*)(vp + r2 * 8);
        const int dbase = (tid >> 6) * 32 + r2 * 8;
        #pragma unroll
        for (int j = 0; j < 8; ++j)
          KV[(dbase + j) * 72 + keyl] = vv[j];
      }
    }
    __syncthreads();
    #pragma unroll
    for (int ks = 0; ks < 2; ++ks){
      const float* sp = &S[(wave * 16 + (lane & 15)) * 196 + c * 64 + ks * 32 + 8 * (lane >> 4)];
      float4 p0 = *(const float4*)sp;
      float4 p1 = *(const float4*)(sp + 4);
      bf16x8 pf;
      pf[0] = (short)f2bf(p0.x); pf[1] = (short)f2bf(p0.y);
      pf[2] = (short)f2bf(p0.z); pf[3] = (short)f2bf(p0.w);
      pf[4] = (short)f2bf(p1.x); pf[5] = (short)f2bf(p1.y);
      pf[6] = (short)f2bf(p1.z); pf[7] = (short)f2bf(p1.w);
      #pragma unroll
      for (int nf = 0; nf < 8; ++nf){
        bf16x8 vf = *(const bf16x8*)(&KV[(nf * 16 + (lane & 15)) * 72 + ks * 32 + 8 * (lane >> 4)]);
        oacc[nf] = __builtin_amdgcn_mfma_f32_16x16x32_bf16(pf, vf, oacc[nf], 0, 0, 0);
      }
    }
    __syncthreads();
  }

  {
    const int b = bh >> 3, h = bh & 7;
    #pragma unroll
    for (int nf = 0; nf < 8; ++nf){
      const int d = nf * 16 + (lane & 15);
      const float gv = gate[h * HD + d];
      #pragma unroll
      for (int j = 0; j < 4; ++j){
        const int t = q0 + wave * 16 + ((lane >> 4) << 2) + j;
        Ao[((size_t)(b * SEQ + t)) * EMB + h * HD + d] = f2bf(oacc[nf][j] * gv);
      }
    }
  }
}

// ---------------- launch ----------------

extern "C" void kernel_launch(void* const* d_in, const int* in_sizes, int n_in,
                              void* d_out, int out_size, void* d_ws, size_t ws_size,
                              hipStream_t stream)
{
  const float* x     = (const float*)d_in[0];
  const float* Wqkv  = (const float*)d_in[1];
  const float* bqkv  = (const float*)d_in[2];
  const float* Wproj = (const float*)d_in[3];
  const float* bproj = (const float*)d_in[4];
  const float* gate  = (const float*)d_in[5];
  float* out = (float*)d_out;

  u16* Xb   = (u16*)d_ws;                        // [4096][1024]
  u16* Wqt  = Xb   + (size_t)MTOT * EMB;         // [3072][1024]
  u16* Wpt  = Wqt  + (size_t)NQKV * EMB;         // [1024][1024]
  u16* QKVb = Wpt  + (size_t)EMB * EMB;          // 3 x [B,H,T,D]
  u16* Ao   = QKVb + (size_t)3 * QKVSZ;          // [4096][1024] gated attn out

  prep<<<dim3(6144), dim3(256), 0, stream>>>(x, Wqkv, Wproj, Xb, Wqt, Wpt);

  gemm_qkv<<<dim3(NQKV / 128, MTOT / 128), dim3(256), 0, stream>>>(Xb, Wqt, bqkv, QKVb);

  attn_kernel<<<dim3(SEQ / 64, NB * NH), dim3(256), 0, stream>>>(QKVb, gate, Ao);

  gemm_proj<<<dim3(EMB / 64, MTOT / 128), dim3(256), 0, stream>>>(Ao, Wpt, bproj, out);
}